// Round 5
// baseline (171.715 us; speedup 1.0000x reference)
//
#include <hip/hip_runtime.h>

#define N_NODES 20000
#define HID     256
#define DEG     32
#define TOPK    16
#define NRB     313      // ceil(20000/64) row-blocks of 64

typedef __attribute__((ext_vector_type(8))) short short8;
typedef __attribute__((ext_vector_type(4))) float f32x4;
typedef __attribute__((ext_vector_type(2))) _Float16 half2_t;

__device__ inline unsigned short f2bf(float f) {
    unsigned u = __float_as_uint(f);
    unsigned r = (u + 0x7FFFu + ((u >> 16) & 1u)) >> 16;  // RNE
    return (unsigned short)r;
}
__device__ inline float bf_lo(unsigned u) { return __uint_as_float(u << 16); }
__device__ inline float bf_hi(unsigned u) { return __uint_as_float(u & 0xFFFF0000u); }

__device__ inline unsigned short f2h(float f) {
    _Float16 h = (_Float16)f;               // v_cvt_f16_f32 (RNE)
    return __builtin_bit_cast(unsigned short, h);
}
__device__ inline half2_t u2h2(unsigned u) { return __builtin_bit_cast(half2_t, u); }

__device__ inline ushort4 cvt4(float4 f) {
    ushort4 o;
    o.x = f2bf(f.x); o.y = f2bf(f.y); o.z = f2bf(f.z); o.w = f2bf(f.w);
    return o;
}

// static xor-lane exchange within 32-lane groups via ds_swizzle (no vaddr).
#define SWZ_X1  0x041F
#define SWZ_X2  0x081F
#define SWZ_X4  0x101F
#define SWZ_X8  0x201F
#define SWZ_X16 0x401F
template<int IMM>
__device__ __forceinline__ float swz(float x) {
    return __uint_as_float((unsigned)__builtin_amdgcn_ds_swizzle(
        (int)__float_as_uint(x), IMM));
}
// static broadcast: dst lane l <- src lane (l & 0x18) | ORM
// bit-mode imm: (xor=0)<<10 | ORM<<5 | and_mask=0x18
template<int ORM>
__device__ __forceinline__ float swzb(float x) {
    return __uint_as_float((unsigned)__builtin_amdgcn_ds_swizzle(
        (int)__float_as_uint(x), (ORM << 5) | 0x18));
}

// ---------------------------------------------------------------------------
// GEMM accumulate core (round-1 structure: 27.6KB LDS -> 5 blocks/CU, 20
// waves/CU; redundant W staging is latency-hidden by occupancy).
// 64x128 tile, BK=64, 256 thr (4 waves), mfma 16x16x32, swapped operands.
// ---------------------------------------------------------------------------
#define PADE 8
__device__ __forceinline__ void gemm_tile64(
    const unsigned short* __restrict__ A, const unsigned short* __restrict__ W,
    int M, int rowbase, int colbase, f32x4 acc[2][4])
{
    __shared__ unsigned short As[64][64 + PADE];
    __shared__ unsigned short Ws[128][64 + PADE];

    const int t    = threadIdx.x;
    const int lane = t & 63;
    const int wave = t >> 6;
    const int wm   = (wave & 1) * 32;
    const int wn   = (wave >> 1) * 64;

    const int lm = lane & 15;
    const int q8 = (lane >> 4) * 8;

    for (int k0 = 0; k0 < 256; k0 += 64) {
        #pragma unroll
        for (int c = 0; c < 2; ++c) {
            int idx = t + 256 * c;
            int row = idx >> 3;
            int col = (idx & 7) * 8;
            int grow = rowbase + row;
            uint4 av = make_uint4(0u, 0u, 0u, 0u);
            if (grow < M) av = *(const uint4*)(A + (size_t)grow * 256 + k0 + col);
            *(uint4*)&As[row][col] = av;
        }
        #pragma unroll
        for (int c = 0; c < 4; ++c) {
            int idx = t + 256 * c;
            int row = idx >> 3;
            int col = (idx & 7) * 8;
            uint4 wv = *(const uint4*)(W + (size_t)(colbase + row) * 256 + k0 + col);
            *(uint4*)&Ws[row][col] = wv;
        }
        __syncthreads();

        #pragma unroll
        for (int kk = 0; kk < 64; kk += 32) {
            short8 af[2], bfr[4];
            #pragma unroll
            for (int i = 0; i < 2; ++i)
                af[i] = *(const short8*)&As[wm + i * 16 + lm][kk + q8];
            #pragma unroll
            for (int j = 0; j < 4; ++j)
                bfr[j] = *(const short8*)&Ws[wn + j * 16 + lm][kk + q8];
            #pragma unroll
            for (int i = 0; i < 2; ++i)
                #pragma unroll
                for (int j = 0; j < 4; ++j)
                    acc[i][j] = __builtin_amdgcn_mfma_f32_16x16x32_bf16(
                        bfr[j], af[i], acc[i][j], 0, 0, 0);   // swapped operands
        }
        __syncthreads();
    }
}

// ---------------------------------------------------------------------------
// Dispatch 0: prep — h fp32->bf16 (once), Wq/Wk/Wv/Wo fp32->bf16 (once, into
// one contiguous Wb buffer), top-16 edge-weight mask + normalize.
// ---------------------------------------------------------------------------
__global__ __launch_bounds__(256) void prep(
    const float* __restrict__ h,
    const float* __restrict__ Wq, const float* __restrict__ Wk,
    const float* __restrict__ Wv, const float* __restrict__ Wo,
    const float* __restrict__ ew,
    unsigned short* __restrict__ hb, unsigned short* __restrict__ Wb,
    float* __restrict__ wgt)
{
    const int id = blockIdx.x;
    const int t  = threadIdx.x;

    if (id < 2500) {                      // ---- h convert ----
        size_t i = ((size_t)id * 256 + t) * 8;
        float4 f0 = *(const float4*)(h + i);
        float4 f1 = *(const float4*)(h + i + 4);
        *(ushort4*)(hb + i)     = cvt4(f0);
        *(ushort4*)(hb + i + 4) = cvt4(f1);
        return;
    }
    if (id < 2628) {                      // ---- W convert ----
        int e = ((id - 2500) * 256 + t) * 8;     // 0..262136
        const float* W = (e < 65536) ? Wq : (e < 131072) ? Wk
                       : (e < 196608) ? Wv : Wo;
        int off = e & 65535;
        float4 f0 = *(const float4*)(W + off);
        float4 f1 = *(const float4*)(W + off + 4);
        *(ushort4*)(Wb + e)     = cvt4(f0);
        *(ushort4*)(Wb + e + 4) = cvt4(f1);
        return;
    }
    // ---- topk ----
    int n = (id - 2628) * 8 + (t >> 5);
    int lane = t & 31;
    float my = ew[n * 32 + lane];
    int cnt = 0;
    #pragma unroll
    for (int j = 0; j < 32; ++j) {
        float o = __shfl(my, j, 32);
        cnt += (o > my || (o == my && j < lane)) ? 1 : 0;
    }
    float w = (cnt < TOPK) ? my : 0.0f;
    float s = w;
    #pragma unroll
    for (int off = 16; off; off >>= 1) s += __shfl_xor(s, off, 32);
    wgt[n * 32 + lane] = w / (s + 1e-5f);
}

// ---------------------------------------------------------------------------
// Dispatch 1: q/k/v projections (round-1 structure). 1920 GEMM blocks,
// XCD-pinned 64-row blocks (id&7), variant=(z,by).
//   q  -> fp16 head-major [8][N][32]
//   kv -> [8][N][64], 16B chunks: chunk c = {k[4c..4c+3] fp16, v[4c..4c+3] bf16}
// ---------------------------------------------------------------------------
__global__ __launch_bounds__(256) void gemm_qkv(
    const unsigned short* __restrict__ A, const unsigned short* __restrict__ Wb,
    const float* __restrict__ bq, const float* __restrict__ bk,
    const float* __restrict__ bv,
    unsigned short* __restrict__ Cq, unsigned short* __restrict__ kvo, int M)
{
    const int id = blockIdx.x;
    const int t  = threadIdx.x;

    const int xcd     = id & 7;
    const int rest    = id >> 3;          // 0..239
    const int rowblk  = xcd + 8 * (rest / 6);
    const int variant = rest % 6;
    if (rowblk >= NRB) return;
    const int z  = variant >> 1;
    const int by = variant & 1;

    const unsigned short* W = Wb + z * 65536;
    const float* bias = (z == 0) ? bq : (z == 1) ? bk : bv;

    f32x4 acc[2][4];
    #pragma unroll
    for (int i = 0; i < 2; ++i)
        #pragma unroll
        for (int j = 0; j < 4; ++j)
            acc[i][j] = (f32x4){0.f, 0.f, 0.f, 0.f};

    gemm_tile64(A, W, M, rowblk * 64, by * 128, acc);

    const int lane = t & 63;
    const int wave = t >> 6;
    const int wm   = (wave & 1) * 32;
    const int wn   = (wave >> 1) * 64;
    const int lm   = lane & 15;
    const int lq   = lane >> 4;

    #pragma unroll
    for (int i = 0; i < 2; ++i) {
        int node = rowblk * 64 + wm + i * 16 + lm;
        if (node >= M) continue;
        #pragma unroll
        for (int j = 0; j < 4; ++j) {
            int col0 = by * 128 + wn + j * 16 + lq * 4;   // 4 consecutive cols
            float4 b4 = *(const float4*)(bias + col0);
            float x0 = acc[i][j][0] + b4.x;
            float x1 = acc[i][j][1] + b4.y;
            float x2 = acc[i][j][2] + b4.z;
            float x3 = acc[i][j][3] + b4.w;
            int hh = col0 >> 5, cc = col0 & 31;
            if (z == 0) {
                ushort4 o; o.x = f2h(x0); o.y = f2h(x1); o.z = f2h(x2); o.w = f2h(x3);
                *(ushort4*)(Cq + (size_t)hh * ((size_t)N_NODES * 32)
                               + (size_t)node * 32 + cc) = o;
            } else if (z == 1) {
                ushort4 o; o.x = f2h(x0); o.y = f2h(x1); o.z = f2h(x2); o.w = f2h(x3);
                *(ushort4*)(kvo + (size_t)hh * ((size_t)N_NODES * 64)
                               + (size_t)node * 64 + (cc >> 2) * 8) = o;
            } else {
                ushort4 o; o.x = f2bf(x0); o.y = f2bf(x1); o.z = f2bf(x2); o.w = f2bf(x3);
                *(ushort4*)(kvo + (size_t)hh * ((size_t)N_NODES * 64)
                               + (size_t)node * 64 + (cc >> 2) * 8 + 4) = o;
            }
        }
    }
}

// ---------------------------------------------------------------------------
// Dispatch 3: o-projection (round-1 structure). fp32 out + fused leaky-relu.
// ---------------------------------------------------------------------------
__global__ __launch_bounds__(256) void gemm_out(
    const unsigned short* __restrict__ A, const unsigned short* __restrict__ W,
    const float* __restrict__ bias, float* __restrict__ out, int M)
{
    const int id     = blockIdx.x;
    const int xcd    = id & 7;
    const int rest   = id >> 3;           // 0..79
    const int rowblk = xcd + 8 * (rest >> 1);
    const int ch     = rest & 1;
    if (rowblk >= NRB) return;

    f32x4 acc[2][4];
    #pragma unroll
    for (int i = 0; i < 2; ++i)
        #pragma unroll
        for (int j = 0; j < 4; ++j)
            acc[i][j] = (f32x4){0.f, 0.f, 0.f, 0.f};

    gemm_tile64(A, W, M, rowblk * 64, ch * 128, acc);

    const int lane = threadIdx.x & 63;
    const int wave = threadIdx.x >> 6;
    const int wm   = (wave & 1) * 32;
    const int wn   = (wave >> 1) * 64;
    const int lm   = lane & 15;
    const int lq   = lane >> 4;

    #pragma unroll
    for (int i = 0; i < 2; ++i) {
        int node = rowblk * 64 + wm + i * 16 + lm;
        if (node >= M) continue;
        #pragma unroll
        for (int j = 0; j < 4; ++j) {
            int col0 = ch * 128 + wn + j * 16 + lq * 4;
            float4 b4 = *(const float4*)(bias + col0);
            float4 o;
            o.x = acc[i][j][0] + b4.x;
            o.y = acc[i][j][1] + b4.y;
            o.z = acc[i][j][2] + b4.z;
            o.w = acc[i][j][3] + b4.w;
            o.x = (o.x >= 0.f) ? o.x : 0.01f * o.x;
            o.y = (o.y >= 0.f) ? o.y : 0.01f * o.y;
            o.z = (o.z >= 0.f) ? o.z : 0.01f * o.z;
            o.w = (o.w >= 0.f) ? o.w : 0.01f * o.w;
            *(float4*)(out + (size_t)node * 256 + col0) = o;
        }
    }
}

// ---------------------------------------------------------------------------
// Dispatch 2: attention, head-sharded (head = blockIdx.x & 7 -> XCD L2 shard).
// NEW: persistent grid-stride blocks — 2000 blocks (8 heads x 250), each
// looping 10 node-octets (stride 250). All 8000 waves resident at once
// (31/CU): no dispatch churn, and the compiler can pipeline iteration i+1's
// independent gathers under iteration i's swizzle chain without the round-3
// VGPR doubling. Per-iteration body identical to round-4 (known-good).
// ---------------------------------------------------------------------------
__global__ __launch_bounds__(256) void attn_shard(
    const unsigned short* __restrict__ qh, const unsigned short* __restrict__ kv,
    const int* __restrict__ nbr, const float* __restrict__ wgt,
    unsigned short* __restrict__ agg)
{
    const int h     = blockIdx.x & 7;
    const int obase = blockIdx.x >> 3;   // 0..249
    const int t     = threadIdx.x;
    const int lane  = t & 31;

    const size_t hkv = (size_t)h * ((size_t)N_NODES * 64);
    const size_t hq  = (size_t)h * ((size_t)N_NODES * 32);

    const int cg = lane & 7;
    const int dg = lane >> 3;            // 0..3

    for (int o = obase; o < 2500; o += 250) {
        const int n = o * 8 + (t >> 5);

        // neighbors this lane gathers: dg + 4j, j = 0..7 — direct coalesced
        int nbj[8];
        #pragma unroll
        for (int j = 0; j < 8; ++j)
            nbj[j] = nbr[n * 32 + dg + 4 * j];
        // edge weight of the neighbor this lane will score (m = dg + 4*cg)
        const float wm = wgt[n * 32 + dg + 4 * cg];

        // one fully-coalesced uint4 per neighbor: chunk cg = 4 k fp16 + 4 v bf16
        uint4 kvr[8];
        #pragma unroll
        for (int j = 0; j < 8; ++j)
            kvr[j] = *(const uint4*)(kv + hkv + (size_t)nbj[j] * 64 + cg * 8);

        // q chunk: 4 fp16 at cols 4cg..4cg+3 (broadcast across dg)
        uint2 qc = *(const uint2*)(qh + hq + (size_t)n * 32 + cg * 4);

        // partial scores (this lane's 4 cols) for its 8 neighbors
        float p[8];
        #pragma unroll
        for (int j = 0; j < 8; ++j) {
            float s = __builtin_amdgcn_fdot2(u2h2(kvr[j].x), u2h2(qc.x), 0.f, false);
            p[j]    = __builtin_amdgcn_fdot2(u2h2(kvr[j].y), u2h2(qc.y), s, false);
        }

        // reduce-scatter over cg (xor 4,2,1): lane ends with dot of nbr dg+4*cg
        const bool b4 = (cg & 4) != 0;
        float q4[4];
        #pragma unroll
        for (int jj = 0; jj < 4; ++jj) {
            float snd = b4 ? p[jj] : p[jj + 4];
            float kp  = b4 ? p[jj + 4] : p[jj];
            q4[jj] = kp + swz<SWZ_X4>(snd);
        }
        const bool b2 = (cg & 2) != 0;
        float q2[2];
        #pragma unroll
        for (int jj = 0; jj < 2; ++jj) {
            float snd = b2 ? q4[jj] : q4[jj + 2];
            float kp  = b2 ? q4[jj + 2] : q4[jj];
            q2[jj] = kp + swz<SWZ_X2>(snd);
        }
        const bool b1 = (cg & 1) != 0;
        float sc;
        {
            float snd = b1 ? q2[0] : q2[1];
            float kp  = b1 ? q2[1] : q2[0];
            sc = kp + swz<SWZ_X1>(snd);
        }

        // logit in exp2 domain; NO max-subtraction (|z| <= ~1, shift-invariant)
        float zl = sc * wm * 0.25500917211914f;      // / sqrt(32) * log2(e)
        float e  = __builtin_amdgcn_exp2f(zl);
        float ssum = e;
        ssum += swz<SWZ_X1>(ssum);
        ssum += swz<SWZ_X2>(ssum);
        ssum += swz<SWZ_X4>(ssum);
        ssum += swz<SWZ_X8>(ssum);
        ssum += swz<SWZ_X16>(ssum);
        const float aw = e * __builtin_amdgcn_rcpf(ssum);

        // v accumulate: aw of neighbor dg+4j lives at lane (lane&0x18)|j
        // -> static ds_swizzle broadcast, no vaddr.
        float a0 = 0.f, a1 = 0.f, a2 = 0.f, a3 = 0.f;
#define VACC(J) { float awv = swzb<J>(aw); \
        a0 = fmaf(awv, bf_lo(kvr[J].z), a0); \
        a1 = fmaf(awv, bf_hi(kvr[J].z), a1); \
        a2 = fmaf(awv, bf_lo(kvr[J].w), a2); \
        a3 = fmaf(awv, bf_hi(kvr[J].w), a3); }
        VACC(0) VACC(1) VACC(2) VACC(3) VACC(4) VACC(5) VACC(6) VACC(7)
#undef VACC

        // reduce-scatter over dg (xor8 then xor16): lane ends with component
        // dg of chunk cg, fully summed.
        const bool r1 = (dg & 1) != 0;
        float s0 = r1 ? a0 : a1;
        float s1 = r1 ? a2 : a3;
        float k0 = r1 ? a1 : a0;
        float k1 = r1 ? a3 : a2;
        k0 += swz<SWZ_X8>(s0);
        k1 += swz<SWZ_X8>(s1);
        const bool r2 = (dg & 2) != 0;
        float s2v = r2 ? k0 : k1;
        float k2v = r2 ? k1 : k0;
        float r = k2v + swz<SWZ_X16>(s2v);

        agg[(size_t)n * 256 + h * 32 + cg * 4 + dg] = f2bf(r);
    }
}

// ---------------------------------------------------------------------------
extern "C" void kernel_launch(void* const* d_in, const int* in_sizes, int n_in,
                              void* d_out, int out_size, void* d_ws, size_t ws_size,
                              hipStream_t stream)
{
    const float* h   = (const float*)d_in[0];
    const int*   nbr = (const int*)  d_in[1];
    const float* ew  = (const float*)d_in[2];
    const float* Wq  = (const float*)d_in[3];
    const float* bq  = (const float*)d_in[4];
    const float* Wk  = (const float*)d_in[5];
    const float* bk  = (const float*)d_in[6];
    const float* Wv  = (const float*)d_in[7];
    const float* bv  = (const float*)d_in[8];
    const float* Wo  = (const float*)d_in[9];
    const float* bo  = (const float*)d_in[10];
    float* out = (float*)d_out;

    const size_t NM = (size_t)N_NODES * HID;   // 5,120,000
    char* ws = (char*)d_ws;
    unsigned short* qb   = (unsigned short*)ws; ws += NM * 2;   // fp16 [8][N][32]
    unsigned short* kvb  = (unsigned short*)ws; ws += NM * 4;   // [8][N][64] 16B-chunk k|v
    unsigned short* aggb = (unsigned short*)ws; ws += NM * 2;   // bf16 [N][256]
    unsigned short* Wbb  = (unsigned short*)ws; ws += 4 * 65536 * 2; // bf16 Wq|Wk|Wv|Wo
    float* wgt = (float*)ws;                    ws += (size_t)N_NODES * 32 * 4;

    // hb (bf16 h) aliases aggb: gemm_qkv (reads hb) completes before
    // attn_shard (writes aggb) by stream ordering.
    unsigned short* hb = aggb;

    dim3 blk(256);

    prep<<<dim3(5128), blk, 0, stream>>>(h, Wq, Wk, Wv, Wo, ew, hb, Wbb, wgt);

    gemm_qkv<<<dim3(1920), blk, 0, stream>>>(hb, Wbb, bq, bk, bv, qb, kvb, N_NODES);

    attn_shard<<<dim3(2000), blk, 0, stream>>>(qb, kvb, nbr, wgt, aggb);

    gemm_out<<<dim3(640), blk, 0, stream>>>(aggb, Wbb + 3 * 65536, bo, out, N_NODES);
}

// Round 6
// 159.340 us; speedup vs baseline: 1.0777x; 1.0777x over previous
//
#include <hip/hip_runtime.h>

#define N_NODES 20000
#define HID     256
#define DEG     32
#define TOPK    16
#define NRB     313      // ceil(20000/64) row-blocks of 64

typedef __attribute__((ext_vector_type(8))) short short8;
typedef __attribute__((ext_vector_type(4))) float f32x4;
typedef __attribute__((ext_vector_type(2))) _Float16 half2_t;

__device__ inline unsigned short f2bf(float f) {
    unsigned u = __float_as_uint(f);
    unsigned r = (u + 0x7FFFu + ((u >> 16) & 1u)) >> 16;  // RNE
    return (unsigned short)r;
}
__device__ inline float bf_lo(unsigned u) { return __uint_as_float(u << 16); }
__device__ inline float bf_hi(unsigned u) { return __uint_as_float(u & 0xFFFF0000u); }

__device__ inline unsigned short f2h(float f) {
    _Float16 h = (_Float16)f;               // v_cvt_f16_f32 (RNE)
    return __builtin_bit_cast(unsigned short, h);
}
__device__ inline half2_t u2h2(unsigned u) { return __builtin_bit_cast(half2_t, u); }

__device__ inline ushort4 cvt4(float4 f) {
    ushort4 o;
    o.x = f2bf(f.x); o.y = f2bf(f.y); o.z = f2bf(f.z); o.w = f2bf(f.w);
    return o;
}

// static xor-lane exchange within 32-lane groups via ds_swizzle (no vaddr).
#define SWZ_X1  0x041F
#define SWZ_X2  0x081F
#define SWZ_X4  0x101F
#define SWZ_X8  0x201F
#define SWZ_X16 0x401F
template<int IMM>
__device__ __forceinline__ float swz(float x) {
    return __uint_as_float((unsigned)__builtin_amdgcn_ds_swizzle(
        (int)__float_as_uint(x), IMM));
}
// static broadcast: dst lane l <- src lane (l & 0x18) | ORM
// bit-mode imm: (xor=0)<<10 | ORM<<5 | and_mask=0x18
template<int ORM>
__device__ __forceinline__ float swzb(float x) {
    return __uint_as_float((unsigned)__builtin_amdgcn_ds_swizzle(
        (int)__float_as_uint(x), (ORM << 5) | 0x18));
}

// ---------------------------------------------------------------------------
// GEMM accumulate core. NEW: staging via global_load_lds width=16 (no VGPR
// round-trip, no ds_write). Linear LDS dest (wave-uniform base + lane*16) +
// PRE-SWIZZLED global source (chunk c <- global chunk c^(row&7)) + same XOR
// on MFMA-fragment reads (rule: both-sides-or-neither). Unpadded tiles:
// As 64x64 (8KB), Ws 128x64 (16KB) -> 24KB LDS, ~6 blocks/CU.
// Read-bank check: lanes lm=0..7 hit 8 distinct bank-quads via the XOR;
// lm=8..15 alias 2-way (free). Tail rows clamp to M-1 (finite, never stored).
// ---------------------------------------------------------------------------
__device__ __forceinline__ void gemm_tile64(
    const unsigned short* __restrict__ A, const unsigned short* __restrict__ W,
    int M, int rowbase, int colbase, f32x4 acc[2][4])
{
    __shared__ unsigned short As[64 * 64];
    __shared__ unsigned short Ws[128 * 64];

    const int t    = threadIdx.x;
    const int lane = t & 63;
    const int wave = t >> 6;
    const int wm   = (wave & 1) * 32;
    const int wn   = (wave >> 1) * 64;

    const int lm = lane & 15;
    const int q8 = (lane >> 4) * 8;
    const int xa = (lm & 7) << 4;          // read-side XOR (row&7 == lm&7)

    for (int k0 = 0; k0 < 256; k0 += 64) {
        // A tile: 64x64 -> 512 16B chunks, 2/thread, direct-to-LDS
        #pragma unroll
        for (int c = 0; c < 2; ++c) {
            int idx = t + 256 * c;
            int row = idx >> 3;
            int c8  = idx & 7;
            int grow = rowbase + row;
            if (grow >= M) grow = M - 1;   // finite dup, outputs never stored
            const unsigned short* g =
                A + (size_t)grow * 256 + k0 + ((c8 ^ (row & 7)) * 8);
            __builtin_amdgcn_global_load_lds(
                (const __attribute__((address_space(1))) void*)g,
                (__attribute__((address_space(3))) void*)((char*)As + idx * 16),
                16, 0, 0);
        }
        // W tile: 128x64 -> 1024 16B chunks, 4/thread, direct-to-LDS
        #pragma unroll
        for (int c = 0; c < 4; ++c) {
            int idx = t + 256 * c;
            int row = idx >> 3;
            int c8  = idx & 7;
            const unsigned short* g =
                W + (size_t)(colbase + row) * 256 + k0 + ((c8 ^ (row & 7)) * 8);
            __builtin_amdgcn_global_load_lds(
                (const __attribute__((address_space(1))) void*)g,
                (__attribute__((address_space(3))) void*)((char*)Ws + idx * 16),
                16, 0, 0);
        }
        __syncthreads();                   // drains vmcnt before barrier

        #pragma unroll
        for (int kk = 0; kk < 64; kk += 32) {
            short8 af[2], bfr[4];
            #pragma unroll
            for (int i = 0; i < 2; ++i)
                af[i] = *(const short8*)((const char*)As
                         + (wm + i * 16 + lm) * 128 + (((kk + q8) * 2) ^ xa));
            #pragma unroll
            for (int j = 0; j < 4; ++j)
                bfr[j] = *(const short8*)((const char*)Ws
                         + (wn + j * 16 + lm) * 128 + (((kk + q8) * 2) ^ xa));
            #pragma unroll
            for (int i = 0; i < 2; ++i)
                #pragma unroll
                for (int j = 0; j < 4; ++j)
                    acc[i][j] = __builtin_amdgcn_mfma_f32_16x16x32_bf16(
                        bfr[j], af[i], acc[i][j], 0, 0, 0);   // swapped operands
        }
        __syncthreads();
    }
}

// ---------------------------------------------------------------------------
// Dispatch 0: prep — h fp32->bf16 (once), Wq/Wk/Wv/Wo fp32->bf16 (once, into
// one contiguous Wb buffer), top-16 edge-weight mask + normalize.
// ---------------------------------------------------------------------------
__global__ __launch_bounds__(256) void prep(
    const float* __restrict__ h,
    const float* __restrict__ Wq, const float* __restrict__ Wk,
    const float* __restrict__ Wv, const float* __restrict__ Wo,
    const float* __restrict__ ew,
    unsigned short* __restrict__ hb, unsigned short* __restrict__ Wb,
    float* __restrict__ wgt)
{
    const int id = blockIdx.x;
    const int t  = threadIdx.x;

    if (id < 2500) {                      // ---- h convert ----
        size_t i = ((size_t)id * 256 + t) * 8;
        float4 f0 = *(const float4*)(h + i);
        float4 f1 = *(const float4*)(h + i + 4);
        *(ushort4*)(hb + i)     = cvt4(f0);
        *(ushort4*)(hb + i + 4) = cvt4(f1);
        return;
    }
    if (id < 2628) {                      // ---- W convert ----
        int e = ((id - 2500) * 256 + t) * 8;     // 0..262136
        const float* W = (e < 65536) ? Wq : (e < 131072) ? Wk
                       : (e < 196608) ? Wv : Wo;
        int off = e & 65535;
        float4 f0 = *(const float4*)(W + off);
        float4 f1 = *(const float4*)(W + off + 4);
        *(ushort4*)(Wb + e)     = cvt4(f0);
        *(ushort4*)(Wb + e + 4) = cvt4(f1);
        return;
    }
    // ---- topk ----
    int n = (id - 2628) * 8 + (t >> 5);
    int lane = t & 31;
    float my = ew[n * 32 + lane];
    int cnt = 0;
    #pragma unroll
    for (int j = 0; j < 32; ++j) {
        float o = __shfl(my, j, 32);
        cnt += (o > my || (o == my && j < lane)) ? 1 : 0;
    }
    float w = (cnt < TOPK) ? my : 0.0f;
    float s = w;
    #pragma unroll
    for (int off = 16; off; off >>= 1) s += __shfl_xor(s, off, 32);
    wgt[n * 32 + lane] = w / (s + 1e-5f);
}

// ---------------------------------------------------------------------------
// Dispatch 1: q/k/v projections (round-1 grid). 1920 GEMM blocks,
// XCD-pinned 64-row blocks (id&7), variant=(z,by).
//   q  -> fp16 head-major [8][N][32]
//   kv -> [8][N][64], 16B chunks: chunk c = {k[4c..4c+3] fp16, v[4c..4c+3] bf16}
// ---------------------------------------------------------------------------
__global__ __launch_bounds__(256) void gemm_qkv(
    const unsigned short* __restrict__ A, const unsigned short* __restrict__ Wb,
    const float* __restrict__ bq, const float* __restrict__ bk,
    const float* __restrict__ bv,
    unsigned short* __restrict__ Cq, unsigned short* __restrict__ kvo, int M)
{
    const int id = blockIdx.x;
    const int t  = threadIdx.x;

    const int xcd     = id & 7;
    const int rest    = id >> 3;          // 0..239
    const int rowblk  = xcd + 8 * (rest / 6);
    const int variant = rest % 6;
    if (rowblk >= NRB) return;
    const int z  = variant >> 1;
    const int by = variant & 1;

    const unsigned short* W = Wb + z * 65536;
    const float* bias = (z == 0) ? bq : (z == 1) ? bk : bv;

    f32x4 acc[2][4];
    #pragma unroll
    for (int i = 0; i < 2; ++i)
        #pragma unroll
        for (int j = 0; j < 4; ++j)
            acc[i][j] = (f32x4){0.f, 0.f, 0.f, 0.f};

    gemm_tile64(A, W, M, rowblk * 64, by * 128, acc);

    const int lane = t & 63;
    const int wave = t >> 6;
    const int wm   = (wave & 1) * 32;
    const int wn   = (wave >> 1) * 64;
    const int lm   = lane & 15;
    const int lq   = lane >> 4;

    #pragma unroll
    for (int i = 0; i < 2; ++i) {
        int node = rowblk * 64 + wm + i * 16 + lm;
        if (node >= M) continue;
        #pragma unroll
        for (int j = 0; j < 4; ++j) {
            int col0 = by * 128 + wn + j * 16 + lq * 4;   // 4 consecutive cols
            float4 b4 = *(const float4*)(bias + col0);
            float x0 = acc[i][j][0] + b4.x;
            float x1 = acc[i][j][1] + b4.y;
            float x2 = acc[i][j][2] + b4.z;
            float x3 = acc[i][j][3] + b4.w;
            int hh = col0 >> 5, cc = col0 & 31;
            if (z == 0) {
                ushort4 o; o.x = f2h(x0); o.y = f2h(x1); o.z = f2h(x2); o.w = f2h(x3);
                *(ushort4*)(Cq + (size_t)hh * ((size_t)N_NODES * 32)
                               + (size_t)node * 32 + cc) = o;
            } else if (z == 1) {
                ushort4 o; o.x = f2h(x0); o.y = f2h(x1); o.z = f2h(x2); o.w = f2h(x3);
                *(ushort4*)(kvo + (size_t)hh * ((size_t)N_NODES * 64)
                               + (size_t)node * 64 + (cc >> 2) * 8) = o;
            } else {
                ushort4 o; o.x = f2bf(x0); o.y = f2bf(x1); o.z = f2bf(x2); o.w = f2bf(x3);
                *(ushort4*)(kvo + (size_t)hh * ((size_t)N_NODES * 64)
                               + (size_t)node * 64 + (cc >> 2) * 8 + 4) = o;
            }
        }
    }
}

// ---------------------------------------------------------------------------
// Dispatch 3: o-projection (round-1 grid). fp32 out + fused leaky-relu.
// ---------------------------------------------------------------------------
__global__ __launch_bounds__(256) void gemm_out(
    const unsigned short* __restrict__ A, const unsigned short* __restrict__ W,
    const float* __restrict__ bias, float* __restrict__ out, int M)
{
    const int id     = blockIdx.x;
    const int xcd    = id & 7;
    const int rest   = id >> 3;           // 0..79
    const int rowblk = xcd + 8 * (rest >> 1);
    const int ch     = rest & 1;
    if (rowblk >= NRB) return;

    f32x4 acc[2][4];
    #pragma unroll
    for (int i = 0; i < 2; ++i)
        #pragma unroll
        for (int j = 0; j < 4; ++j)
            acc[i][j] = (f32x4){0.f, 0.f, 0.f, 0.f};

    gemm_tile64(A, W, M, rowblk * 64, ch * 128, acc);

    const int lane = threadIdx.x & 63;
    const int wave = threadIdx.x >> 6;
    const int wm   = (wave & 1) * 32;
    const int wn   = (wave >> 1) * 64;
    const int lm   = lane & 15;
    const int lq   = lane >> 4;

    #pragma unroll
    for (int i = 0; i < 2; ++i) {
        int node = rowblk * 64 + wm + i * 16 + lm;
        if (node >= M) continue;
        #pragma unroll
        for (int j = 0; j < 4; ++j) {
            int col0 = ch * 128 + wn + j * 16 + lq * 4;
            float4 b4 = *(const float4*)(bias + col0);
            float4 o;
            o.x = acc[i][j][0] + b4.x;
            o.y = acc[i][j][1] + b4.y;
            o.z = acc[i][j][2] + b4.z;
            o.w = acc[i][j][3] + b4.w;
            o.x = (o.x >= 0.f) ? o.x : 0.01f * o.x;
            o.y = (o.y >= 0.f) ? o.y : 0.01f * o.y;
            o.z = (o.z >= 0.f) ? o.z : 0.01f * o.z;
            o.w = (o.w >= 0.f) ? o.w : 0.01f * o.w;
            *(float4*)(out + (size_t)node * 256 + col0) = o;
        }
    }
}

// ---------------------------------------------------------------------------
// Dispatch 2: attention, head-sharded (head = blockIdx.x & 7 -> XCD L2 shard).
// ROUND-4 structure verbatim (best measured): 20000 one-shot blocks, single
// node-octet per block, static ds_swizzle broadcasts, no softmax max-pass.
// (2-node ILP and persistent-grid variants both regressed: this kernel lives
// off TLP; occupancy > per-wave work.)
// ---------------------------------------------------------------------------
__global__ __launch_bounds__(256) void attn_shard(
    const unsigned short* __restrict__ qh, const unsigned short* __restrict__ kv,
    const int* __restrict__ nbr, const float* __restrict__ wgt,
    unsigned short* __restrict__ agg)
{
    const int h    = blockIdx.x & 7;
    const int t    = threadIdx.x;
    const int lane = t & 31;
    const int n    = (blockIdx.x >> 3) * 8 + (t >> 5);

    const size_t hkv = (size_t)h * ((size_t)N_NODES * 64);
    const size_t hq  = (size_t)h * ((size_t)N_NODES * 32);

    const int cg = lane & 7;
    const int dg = lane >> 3;            // 0..3

    // neighbors this lane gathers: dg + 4j, j = 0..7 — direct coalesced loads
    int nbj[8];
    #pragma unroll
    for (int j = 0; j < 8; ++j)
        nbj[j] = nbr[n * 32 + dg + 4 * j];
    // edge weight of the neighbor this lane will score (m = dg + 4*cg)
    const float wm = wgt[n * 32 + dg + 4 * cg];

    // one fully-coalesced uint4 per neighbor: chunk cg = 4 k fp16 + 4 v bf16
    uint4 kvr[8];
    #pragma unroll
    for (int j = 0; j < 8; ++j)
        kvr[j] = *(const uint4*)(kv + hkv + (size_t)nbj[j] * 64 + cg * 8);

    // q chunk: 4 fp16 at cols 4cg..4cg+3 (broadcast across dg)
    uint2 qc = *(const uint2*)(qh + hq + (size_t)n * 32 + cg * 4);

    // partial scores (this lane's 4 cols) for its 8 neighbors
    float p[8];
    #pragma unroll
    for (int j = 0; j < 8; ++j) {
        float s = __builtin_amdgcn_fdot2(u2h2(kvr[j].x), u2h2(qc.x), 0.f, false);
        p[j]    = __builtin_amdgcn_fdot2(u2h2(kvr[j].y), u2h2(qc.y), s, false);
    }

    // reduce-scatter over cg (xor 4,2,1): lane ends with dot of nbr dg+4*cg
    const bool b4 = (cg & 4) != 0;
    float q4[4];
    #pragma unroll
    for (int jj = 0; jj < 4; ++jj) {
        float snd = b4 ? p[jj] : p[jj + 4];
        float kp  = b4 ? p[jj + 4] : p[jj];
        q4[jj] = kp + swz<SWZ_X4>(snd);
    }
    const bool b2 = (cg & 2) != 0;
    float q2[2];
    #pragma unroll
    for (int jj = 0; jj < 2; ++jj) {
        float snd = b2 ? q4[jj] : q4[jj + 2];
        float kp  = b2 ? q4[jj + 2] : q4[jj];
        q2[jj] = kp + swz<SWZ_X2>(snd);
    }
    const bool b1 = (cg & 1) != 0;
    float sc;
    {
        float snd = b1 ? q2[0] : q2[1];
        float kp  = b1 ? q2[1] : q2[0];
        sc = kp + swz<SWZ_X1>(snd);
    }

    // logit in exp2 domain; NO max-subtraction: |z| <= ~1 (w<=1, |sc| small),
    // softmax is shift-invariant so result is mathematically identical.
    float zl = sc * wm * 0.25500917211914f;          // / sqrt(32) * log2(e)
    float e  = __builtin_amdgcn_exp2f(zl);
    float ssum = e;
    ssum += swz<SWZ_X1>(ssum);
    ssum += swz<SWZ_X2>(ssum);
    ssum += swz<SWZ_X4>(ssum);
    ssum += swz<SWZ_X8>(ssum);
    ssum += swz<SWZ_X16>(ssum);
    const float aw = e * __builtin_amdgcn_rcpf(ssum);   // attn weight of nbr dg+4cg

    // v accumulate: cols 4cg..4cg+3; aw of neighbor dg+4j lives at lane
    // (lane&0x18)|j -> static ds_swizzle broadcast, no vaddr.
    float a0 = 0.f, a1 = 0.f, a2 = 0.f, a3 = 0.f;
#define VACC(J) { float awv = swzb<J>(aw); \
        a0 = fmaf(awv, bf_lo(kvr[J].z), a0); \
        a1 = fmaf(awv, bf_hi(kvr[J].z), a1); \
        a2 = fmaf(awv, bf_lo(kvr[J].w), a2); \
        a3 = fmaf(awv, bf_hi(kvr[J].w), a3); }
    VACC(0) VACC(1) VACC(2) VACC(3) VACC(4) VACC(5) VACC(6) VACC(7)
#undef VACC

    // reduce-scatter over dg (xor8 then xor16): lane ends with component dg
    // of chunk cg, fully summed over all 4 dg partials.
    const bool r1 = (dg & 1) != 0;
    float s0 = r1 ? a0 : a1;
    float s1 = r1 ? a2 : a3;
    float k0 = r1 ? a1 : a0;
    float k1 = r1 ? a3 : a2;
    k0 += swz<SWZ_X8>(s0);
    k1 += swz<SWZ_X8>(s1);
    const bool r2 = (dg & 2) != 0;
    float s2v = r2 ? k0 : k1;
    float k2v = r2 ? k1 : k0;
    float r = k2v + swz<SWZ_X16>(s2v);

    agg[(size_t)n * 256 + h * 32 + cg * 4 + dg] = f2bf(r);
}

// ---------------------------------------------------------------------------
extern "C" void kernel_launch(void* const* d_in, const int* in_sizes, int n_in,
                              void* d_out, int out_size, void* d_ws, size_t ws_size,
                              hipStream_t stream)
{
    const float* h   = (const float*)d_in[0];
    const int*   nbr = (const int*)  d_in[1];
    const float* ew  = (const float*)d_in[2];
    const float* Wq  = (const float*)d_in[3];
    const float* bq  = (const float*)d_in[4];
    const float* Wk  = (const float*)d_in[5];
    const float* bk  = (const float*)d_in[6];
    const float* Wv  = (const float*)d_in[7];
    const float* bv  = (const float*)d_in[8];
    const float* Wo  = (const float*)d_in[9];
    const float* bo  = (const float*)d_in[10];
    float* out = (float*)d_out;

    const size_t NM = (size_t)N_NODES * HID;   // 5,120,000
    char* ws = (char*)d_ws;
    unsigned short* qb   = (unsigned short*)ws; ws += NM * 2;   // fp16 [8][N][32]
    unsigned short* kvb  = (unsigned short*)ws; ws += NM * 4;   // [8][N][64] 16B-chunk k|v
    unsigned short* aggb = (unsigned short*)ws; ws += NM * 2;   // bf16 [N][256]
    unsigned short* Wbb  = (unsigned short*)ws; ws += 4 * 65536 * 2; // bf16 Wq|Wk|Wv|Wo
    float* wgt = (float*)ws;                    ws += (size_t)N_NODES * 32 * 4;

    // hb (bf16 h) aliases aggb: gemm_qkv (reads hb) completes before
    // attn_shard (writes aggb) by stream ordering.
    unsigned short* hb = aggb;

    dim3 blk(256);

    prep<<<dim3(5128), blk, 0, stream>>>(h, Wq, Wk, Wv, Wo, ew, hb, Wbb, wgt);

    gemm_qkv<<<dim3(1920), blk, 0, stream>>>(hb, Wbb, bq, bk, bv, qb, kvb, N_NODES);

    attn_shard<<<dim3(20000), blk, 0, stream>>>(qb, kvb, nbr, wgt, aggb);

    gemm_out<<<dim3(640), blk, 0, stream>>>(aggb, Wbb + 3 * 65536, bo, out, N_NODES);
}

// Round 7
// 157.513 us; speedup vs baseline: 1.0902x; 1.0116x over previous
//
#include <hip/hip_runtime.h>

#define N_NODES 20000
#define HID     256
#define DEG     32
#define TOPK    16
#define NRB     313      // ceil(20000/64) row-blocks of 64

typedef __attribute__((ext_vector_type(8))) short short8;
typedef __attribute__((ext_vector_type(8))) _Float16 half8;
typedef __attribute__((ext_vector_type(4))) float f32x4;
typedef __attribute__((ext_vector_type(2))) float f32x2;
typedef __attribute__((ext_vector_type(2))) _Float16 half2_t;

__device__ inline unsigned short f2bf(float f) {
    unsigned u = __float_as_uint(f);
    unsigned r = (u + 0x7FFFu + ((u >> 16) & 1u)) >> 16;  // RNE
    return (unsigned short)r;
}
__device__ inline float bf_lo(unsigned u) { return __uint_as_float(u << 16); }
__device__ inline float bf_hi(unsigned u) { return __uint_as_float(u & 0xFFFF0000u); }

__device__ inline unsigned short f2h(float f) {
    _Float16 h = (_Float16)f;               // v_cvt_f16_f32 (RNE)
    return __builtin_bit_cast(unsigned short, h);
}
__device__ inline half2_t u2h2(unsigned u) { return __builtin_bit_cast(half2_t, u); }

__device__ inline ushort4 cvt4(float4 f) {
    ushort4 o;
    o.x = f2bf(f.x); o.y = f2bf(f.y); o.z = f2bf(f.z); o.w = f2bf(f.w);
    return o;
}
__device__ inline ushort4 cvt4h(float4 f) {
    ushort4 o;
    o.x = f2h(f.x); o.y = f2h(f.y); o.z = f2h(f.z); o.w = f2h(f.w);
    return o;
}

// static xor-lane exchange within 32-lane groups via ds_swizzle (no vaddr).
#define SWZ_X1  0x041F
#define SWZ_X2  0x081F
#define SWZ_X4  0x101F
#define SWZ_X8  0x201F
#define SWZ_X16 0x401F
template<int IMM>
__device__ __forceinline__ float swz(float x) {
    return __uint_as_float((unsigned)__builtin_amdgcn_ds_swizzle(
        (int)__float_as_uint(x), IMM));
}
// static broadcast: dst lane l <- src lane (l & 0x18) | ORM
template<int ORM>
__device__ __forceinline__ float swzb(float x) {
    return __uint_as_float((unsigned)__builtin_amdgcn_ds_swizzle(
        (int)__float_as_uint(x), (ORM << 5) | 0x18));
}

// ---------------------------------------------------------------------------
// GEMM accumulate core: staging via global_load_lds width=16 (no VGPR
// round-trip, no ds_write). Linear LDS dest + PRE-SWIZZLED global source
// (chunk c <- global chunk c^(row&7)) + same XOR on MFMA-fragment reads.
// Unpadded tiles: As 8KB, Ws 16KB -> 24KB LDS, ~6 blocks/CU.
// F16=1: operands are fp16, use mfma_*_f16 (same register shape as bf16).
// ---------------------------------------------------------------------------
template<int F16>
__device__ __forceinline__ void gemm_tile64(
    const unsigned short* __restrict__ A, const unsigned short* __restrict__ W,
    int M, int rowbase, int colbase, f32x4 acc[2][4])
{
    __shared__ unsigned short As[64 * 64];
    __shared__ unsigned short Ws[128 * 64];

    const int t    = threadIdx.x;
    const int lane = t & 63;
    const int wave = t >> 6;
    const int wm   = (wave & 1) * 32;
    const int wn   = (wave >> 1) * 64;

    const int lm = lane & 15;
    const int q8 = (lane >> 4) * 8;
    const int xa = (lm & 7) << 4;          // read-side XOR (row&7 == lm&7)

    // hoisted per-thread A-row clamps (row fixed across k-steps)
    int growA[2];
    #pragma unroll
    for (int c = 0; c < 2; ++c) {
        int idx = t + 256 * c;
        int g = rowbase + (idx >> 3);
        growA[c] = (g >= M) ? (M - 1) : g;   // finite dup, outputs never stored
    }

    for (int k0 = 0; k0 < 256; k0 += 64) {
        // A tile: 64x64 -> 512 16B chunks, 2/thread, direct-to-LDS
        #pragma unroll
        for (int c = 0; c < 2; ++c) {
            int idx = t + 256 * c;
            int row = idx >> 3;
            int c8  = idx & 7;
            const unsigned short* g =
                A + (size_t)growA[c] * 256 + k0 + ((c8 ^ (row & 7)) * 8);
            __builtin_amdgcn_global_load_lds(
                (const __attribute__((address_space(1))) void*)g,
                (__attribute__((address_space(3))) void*)((char*)As + idx * 16),
                16, 0, 0);
        }
        // W tile: 128x64 -> 1024 16B chunks, 4/thread, direct-to-LDS
        #pragma unroll
        for (int c = 0; c < 4; ++c) {
            int idx = t + 256 * c;
            int row = idx >> 3;
            int c8  = idx & 7;
            const unsigned short* g =
                W + (size_t)(colbase + row) * 256 + k0 + ((c8 ^ (row & 7)) * 8);
            __builtin_amdgcn_global_load_lds(
                (const __attribute__((address_space(1))) void*)g,
                (__attribute__((address_space(3))) void*)((char*)Ws + idx * 16),
                16, 0, 0);
        }
        __syncthreads();                   // drains vmcnt before barrier

        #pragma unroll
        for (int kk = 0; kk < 64; kk += 32) {
            short8 af[2], bfr[4];
            #pragma unroll
            for (int i = 0; i < 2; ++i)
                af[i] = *(const short8*)((const char*)As
                         + (wm + i * 16 + lm) * 128 + (((kk + q8) * 2) ^ xa));
            #pragma unroll
            for (int j = 0; j < 4; ++j)
                bfr[j] = *(const short8*)((const char*)Ws
                         + (wn + j * 16 + lm) * 128 + (((kk + q8) * 2) ^ xa));
            #pragma unroll
            for (int i = 0; i < 2; ++i)
                #pragma unroll
                for (int j = 0; j < 4; ++j) {
                    if constexpr (F16) {
                        acc[i][j] = __builtin_amdgcn_mfma_f32_16x16x32_f16(
                            __builtin_bit_cast(half8, bfr[j]),
                            __builtin_bit_cast(half8, af[i]),
                            acc[i][j], 0, 0, 0);          // swapped operands
                    } else {
                        acc[i][j] = __builtin_amdgcn_mfma_f32_16x16x32_bf16(
                            bfr[j], af[i], acc[i][j], 0, 0, 0);
                    }
                }
        }
        __syncthreads();
    }
}

// ---------------------------------------------------------------------------
// Dispatch 0: prep — h fp32->bf16 (once), Wq/Wk/Wv fp32->bf16, Wo fp32->FP16
// (gemm_out runs f16 MFMA now), top-16 edge-weight mask + normalize.
// ---------------------------------------------------------------------------
__global__ __launch_bounds__(256) void prep(
    const float* __restrict__ h,
    const float* __restrict__ Wq, const float* __restrict__ Wk,
    const float* __restrict__ Wv, const float* __restrict__ Wo,
    const float* __restrict__ ew,
    unsigned short* __restrict__ hb, unsigned short* __restrict__ Wb,
    float* __restrict__ wgt)
{
    const int id = blockIdx.x;
    const int t  = threadIdx.x;

    if (id < 2500) {                      // ---- h convert ----
        size_t i = ((size_t)id * 256 + t) * 8;
        float4 f0 = *(const float4*)(h + i);
        float4 f1 = *(const float4*)(h + i + 4);
        *(ushort4*)(hb + i)     = cvt4(f0);
        *(ushort4*)(hb + i + 4) = cvt4(f1);
        return;
    }
    if (id < 2628) {                      // ---- W convert ----
        int e = ((id - 2500) * 256 + t) * 8;     // 0..262136
        const float* W = (e < 65536) ? Wq : (e < 131072) ? Wk
                       : (e < 196608) ? Wv : Wo;
        int off = e & 65535;
        float4 f0 = *(const float4*)(W + off);
        float4 f1 = *(const float4*)(W + off + 4);
        if (e < 196608) {                 // q/k/v weights: bf16
            *(ushort4*)(Wb + e)     = cvt4(f0);
            *(ushort4*)(Wb + e + 4) = cvt4(f1);
        } else {                          // Wo: fp16
            *(ushort4*)(Wb + e)     = cvt4h(f0);
            *(ushort4*)(Wb + e + 4) = cvt4h(f1);
        }
        return;
    }
    // ---- topk ----
    int n = (id - 2628) * 8 + (t >> 5);
    int lane = t & 31;
    float my = ew[n * 32 + lane];
    int cnt = 0;
    #pragma unroll
    for (int j = 0; j < 32; ++j) {
        float o = __shfl(my, j, 32);
        cnt += (o > my || (o == my && j < lane)) ? 1 : 0;
    }
    float w = (cnt < TOPK) ? my : 0.0f;
    float s = w;
    #pragma unroll
    for (int off = 16; off; off >>= 1) s += __shfl_xor(s, off, 32);
    wgt[n * 32 + lane] = w / (s + 1e-5f);
}

// ---------------------------------------------------------------------------
// Dispatch 1: q/k/v projections. 1920 GEMM blocks, XCD-pinned 64-row blocks
// (id&7), variant=(z,by).
//   q  -> fp16 head-major [8][N][32]
//   kv -> [8][N][64], 16B chunks: chunk c = {k[4c..4c+3] fp16, v[4c..4c+3] bf16}
// ---------------------------------------------------------------------------
__global__ __launch_bounds__(256) void gemm_qkv(
    const unsigned short* __restrict__ A, const unsigned short* __restrict__ Wb,
    const float* __restrict__ bq, const float* __restrict__ bk,
    const float* __restrict__ bv,
    unsigned short* __restrict__ Cq, unsigned short* __restrict__ kvo, int M)
{
    const int id = blockIdx.x;
    const int t  = threadIdx.x;

    const int xcd     = id & 7;
    const int rest    = id >> 3;          // 0..239
    const int rowblk  = xcd + 8 * (rest / 6);
    const int variant = rest % 6;
    if (rowblk >= NRB) return;
    const int z  = variant >> 1;
    const int by = variant & 1;

    const unsigned short* W = Wb + z * 65536;
    const float* bias = (z == 0) ? bq : (z == 1) ? bk : bv;

    f32x4 acc[2][4];
    #pragma unroll
    for (int i = 0; i < 2; ++i)
        #pragma unroll
        for (int j = 0; j < 4; ++j)
            acc[i][j] = (f32x4){0.f, 0.f, 0.f, 0.f};

    gemm_tile64<0>(A, W, M, rowblk * 64, by * 128, acc);

    const int lane = t & 63;
    const int wave = t >> 6;
    const int wm   = (wave & 1) * 32;
    const int wn   = (wave >> 1) * 64;
    const int lm   = lane & 15;
    const int lq   = lane >> 4;

    #pragma unroll
    for (int i = 0; i < 2; ++i) {
        int node = rowblk * 64 + wm + i * 16 + lm;
        if (node >= M) continue;
        #pragma unroll
        for (int j = 0; j < 4; ++j) {
            int col0 = by * 128 + wn + j * 16 + lq * 4;   // 4 consecutive cols
            float4 b4 = *(const float4*)(bias + col0);
            float x0 = acc[i][j][0] + b4.x;
            float x1 = acc[i][j][1] + b4.y;
            float x2 = acc[i][j][2] + b4.z;
            float x3 = acc[i][j][3] + b4.w;
            int hh = col0 >> 5, cc = col0 & 31;
            if (z == 0) {
                ushort4 o; o.x = f2h(x0); o.y = f2h(x1); o.z = f2h(x2); o.w = f2h(x3);
                *(ushort4*)(Cq + (size_t)hh * ((size_t)N_NODES * 32)
                               + (size_t)node * 32 + cc) = o;
            } else if (z == 1) {
                ushort4 o; o.x = f2h(x0); o.y = f2h(x1); o.z = f2h(x2); o.w = f2h(x3);
                *(ushort4*)(kvo + (size_t)hh * ((size_t)N_NODES * 64)
                               + (size_t)node * 64 + (cc >> 2) * 8) = o;
            } else {
                ushort4 o; o.x = f2bf(x0); o.y = f2bf(x1); o.z = f2bf(x2); o.w = f2bf(x3);
                *(ushort4*)(kvo + (size_t)hh * ((size_t)N_NODES * 64)
                               + (size_t)node * 64 + (cc >> 2) * 8 + 4) = o;
            }
        }
    }
}

// ---------------------------------------------------------------------------
// Dispatch 3: o-projection, now FP16 MFMA (agg fp16 x Wo fp16 — both have
// better mantissa than bf16). fp32 out + fused leaky-relu.
// ---------------------------------------------------------------------------
__global__ __launch_bounds__(256) void gemm_out(
    const unsigned short* __restrict__ A, const unsigned short* __restrict__ W,
    const float* __restrict__ bias, float* __restrict__ out, int M)
{
    const int id     = blockIdx.x;
    const int xcd    = id & 7;
    const int rest   = id >> 3;           // 0..79
    const int rowblk = xcd + 8 * (rest >> 1);
    const int ch     = rest & 1;
    if (rowblk >= NRB) return;

    f32x4 acc[2][4];
    #pragma unroll
    for (int i = 0; i < 2; ++i)
        #pragma unroll
        for (int j = 0; j < 4; ++j)
            acc[i][j] = (f32x4){0.f, 0.f, 0.f, 0.f};

    gemm_tile64<1>(A, W, M, rowblk * 64, ch * 128, acc);

    const int lane = threadIdx.x & 63;
    const int wave = threadIdx.x >> 6;
    const int wm   = (wave & 1) * 32;
    const int wn   = (wave >> 1) * 64;
    const int lm   = lane & 15;
    const int lq   = lane >> 4;

    #pragma unroll
    for (int i = 0; i < 2; ++i) {
        int node = rowblk * 64 + wm + i * 16 + lm;
        if (node >= M) continue;
        #pragma unroll
        for (int j = 0; j < 4; ++j) {
            int col0 = ch * 128 + wn + j * 16 + lq * 4;
            float4 b4 = *(const float4*)(bias + col0);
            float4 o;
            o.x = acc[i][j][0] + b4.x;
            o.y = acc[i][j][1] + b4.y;
            o.z = acc[i][j][2] + b4.z;
            o.w = acc[i][j][3] + b4.w;
            o.x = (o.x >= 0.f) ? o.x : 0.01f * o.x;
            o.y = (o.y >= 0.f) ? o.y : 0.01f * o.y;
            o.z = (o.z >= 0.f) ? o.z : 0.01f * o.z;
            o.w = (o.w >= 0.f) ? o.w : 0.01f * o.w;
            *(float4*)(out + (size_t)node * 256 + col0) = o;
        }
    }
}

// ---------------------------------------------------------------------------
// Dispatch 2: attention, head-sharded (head = blockIdx.x & 7 -> XCD L2 shard).
// Round-4 structure (best measured; VALU-issue-bound per census: ~140 VALU /
// lane-node). This rev cuts VALU issue: (1) PV accumulate as f32x2 vectors ->
// v_pk_fma_f32 (16 packed vs 32 scalar fma); (2) agg stored fp16 (1-instr
// f2h vs 4-instr manual bf16 RNE).
// ---------------------------------------------------------------------------
__global__ __launch_bounds__(256) void attn_shard(
    const unsigned short* __restrict__ qh, const unsigned short* __restrict__ kv,
    const int* __restrict__ nbr, const float* __restrict__ wgt,
    unsigned short* __restrict__ agg)
{
    const int h    = blockIdx.x & 7;
    const int t    = threadIdx.x;
    const int lane = t & 31;
    const int n    = (blockIdx.x >> 3) * 8 + (t >> 5);

    const size_t hkv = (size_t)h * ((size_t)N_NODES * 64);
    const size_t hq  = (size_t)h * ((size_t)N_NODES * 32);

    const int cg = lane & 7;
    const int dg = lane >> 3;            // 0..3

    // neighbors this lane gathers: dg + 4j, j = 0..7 — direct coalesced loads
    int nbj[8];
    #pragma unroll
    for (int j = 0; j < 8; ++j)
        nbj[j] = nbr[n * 32 + dg + 4 * j];
    // edge weight of the neighbor this lane will score (m = dg + 4*cg)
    const float wm = wgt[n * 32 + dg + 4 * cg];

    // one fully-coalesced uint4 per neighbor: chunk cg = 4 k fp16 + 4 v bf16
    const unsigned short* kvp = kv + hkv + cg * 8;   // hoisted gather base
    uint4 kvr[8];
    #pragma unroll
    for (int j = 0; j < 8; ++j)
        kvr[j] = *(const uint4*)(kvp + (size_t)nbj[j] * 64);

    // q chunk: 4 fp16 at cols 4cg..4cg+3 (broadcast across dg)
    uint2 qc = *(const uint2*)(qh + hq + (size_t)n * 32 + cg * 4);

    // partial scores (this lane's 4 cols) for its 8 neighbors
    float p[8];
    #pragma unroll
    for (int j = 0; j < 8; ++j) {
        float s = __builtin_amdgcn_fdot2(u2h2(kvr[j].x), u2h2(qc.x), 0.f, false);
        p[j]    = __builtin_amdgcn_fdot2(u2h2(kvr[j].y), u2h2(qc.y), s, false);
    }

    // reduce-scatter over cg (xor 4,2,1): lane ends with dot of nbr dg+4*cg
    const bool b4 = (cg & 4) != 0;
    float q4[4];
    #pragma unroll
    for (int jj = 0; jj < 4; ++jj) {
        float snd = b4 ? p[jj] : p[jj + 4];
        float kp  = b4 ? p[jj + 4] : p[jj];
        q4[jj] = kp + swz<SWZ_X4>(snd);
    }
    const bool b2 = (cg & 2) != 0;
    float q2[2];
    #pragma unroll
    for (int jj = 0; jj < 2; ++jj) {
        float snd = b2 ? q4[jj] : q4[jj + 2];
        float kp  = b2 ? q4[jj + 2] : q4[jj];
        q2[jj] = kp + swz<SWZ_X2>(snd);
    }
    const bool b1 = (cg & 1) != 0;
    float sc;
    {
        float snd = b1 ? q2[0] : q2[1];
        float kp  = b1 ? q2[1] : q2[0];
        sc = kp + swz<SWZ_X1>(snd);
    }

    // logit in exp2 domain; NO max-subtraction: |z| <= ~1 (w<=1, |sc| small),
    // softmax is shift-invariant so result is mathematically identical.
    float zl = sc * wm * 0.25500917211914f;          // / sqrt(32) * log2(e)
    float e  = __builtin_amdgcn_exp2f(zl);
    float ssum = e;
    ssum += swz<SWZ_X1>(ssum);
    ssum += swz<SWZ_X2>(ssum);
    ssum += swz<SWZ_X4>(ssum);
    ssum += swz<SWZ_X8>(ssum);
    ssum += swz<SWZ_X16>(ssum);
    const float aw = e * __builtin_amdgcn_rcpf(ssum);   // attn weight of nbr dg+4cg

    // v accumulate: cols 4cg..4cg+3; aw of neighbor dg+4j lives at lane
    // (lane&0x18)|j -> static ds_swizzle broadcast, no vaddr.
    // f32x2-packed accumulators -> v_pk_fma_f32 (same fma RNE per component).
    f32x2 A01 = {0.f, 0.f}, A23 = {0.f, 0.f};
#define VACC(J) { float awv = swzb<J>(aw); \
        f32x2 w2  = {awv, awv}; \
        f32x2 v01 = {bf_lo(kvr[J].z), bf_hi(kvr[J].z)}; \
        f32x2 v23 = {bf_lo(kvr[J].w), bf_hi(kvr[J].w)}; \
        A01 += w2 * v01; \
        A23 += w2 * v23; }
    VACC(0) VACC(1) VACC(2) VACC(3) VACC(4) VACC(5) VACC(6) VACC(7)
#undef VACC
    float a0 = A01[0], a1 = A01[1], a2 = A23[0], a3 = A23[1];

    // reduce-scatter over dg (xor8 then xor16): lane ends with component dg
    // of chunk cg, fully summed over all 4 dg partials.
    const bool r1 = (dg & 1) != 0;
    float s0 = r1 ? a0 : a1;
    float s1 = r1 ? a2 : a3;
    float k0 = r1 ? a1 : a0;
    float k1 = r1 ? a3 : a2;
    k0 += swz<SWZ_X8>(s0);
    k1 += swz<SWZ_X8>(s1);
    const bool r2 = (dg & 2) != 0;
    float s2v = r2 ? k0 : k1;
    float k2v = r2 ? k1 : k0;
    float r = k2v + swz<SWZ_X16>(s2v);

    agg[(size_t)n * 256 + h * 32 + cg * 4 + dg] = f2h(r);   // fp16 agg
}

// ---------------------------------------------------------------------------
extern "C" void kernel_launch(void* const* d_in, const int* in_sizes, int n_in,
                              void* d_out, int out_size, void* d_ws, size_t ws_size,
                              hipStream_t stream)
{
    const float* h   = (const float*)d_in[0];
    const int*   nbr = (const int*)  d_in[1];
    const float* ew  = (const float*)d_in[2];
    const float* Wq  = (const float*)d_in[3];
    const float* bq  = (const float*)d_in[4];
    const float* Wk  = (const float*)d_in[5];
    const float* bk  = (const float*)d_in[6];
    const float* Wv  = (const float*)d_in[7];
    const float* bv  = (const float*)d_in[8];
    const float* Wo  = (const float*)d_in[9];
    const float* bo  = (const float*)d_in[10];
    float* out = (float*)d_out;

    const size_t NM = (size_t)N_NODES * HID;   // 5,120,000
    char* ws = (char*)d_ws;
    unsigned short* qb   = (unsigned short*)ws; ws += NM * 2;   // fp16 [8][N][32]
    unsigned short* kvb  = (unsigned short*)ws; ws += NM * 4;   // [8][N][64] 16B-chunk k|v
    unsigned short* aggb = (unsigned short*)ws; ws += NM * 2;   // fp16 [N][256]
    unsigned short* Wbb  = (unsigned short*)ws; ws += 4 * 65536 * 2; // Wq|Wk|Wv bf16, Wo fp16
    float* wgt = (float*)ws;                    ws += (size_t)N_NODES * 32 * 4;

    // hb (bf16 h) aliases aggb: gemm_qkv (reads hb) completes before
    // attn_shard (writes aggb) by stream ordering.
    unsigned short* hb = aggb;

    dim3 blk(256);

    prep<<<dim3(5128), blk, 0, stream>>>(h, Wq, Wk, Wv, Wo, ew, hb, Wbb, wgt);

    gemm_qkv<<<dim3(1920), blk, 0, stream>>>(hb, Wbb, bq, bk, bv, qb, kvb, N_NODES);

    attn_shard<<<dim3(20000), blk, 0, stream>>>(qb, kvb, nbr, wgt, aggb);

    gemm_out<<<dim3(640), blk, 0, stream>>>(aggb, Wbb + 3 * 65536, bo, out, N_NODES);
}